// Round 2
// baseline (739.274 us; speedup 1.0000x reference)
//
#include <hip/hip_runtime.h>
#include <cstdint>

#define BT 4096
#define H  2048
#define V  32000
#define BM 256
#define BN 256
#define BK 128          // fp8 bytes == elements per K-tile
#define NRT (BT/BM)     // 16
#define NVT (V/BN)      // 125
#define PJ  128         // padded partials row stride (floats)
#define WSCALE 64.0f
#define INV_WSCALE 0.015625f

typedef int   v8i   __attribute__((ext_vector_type(8)));
typedef float f32x4 __attribute__((ext_vector_type(4)));
typedef float f4v   __attribute__((ext_vector_type(4)));

__device__ __forceinline__ void async_load16(const void* g, void* l) {
    __builtin_amdgcn_global_load_lds(
        (__attribute__((address_space(1))) uint32_t*)(void*)g,
        (__attribute__((address_space(3))) uint32_t*)l, 16, 0, 0);
}

// ------- quantize X and W fp32 -> fp8 e4m3 in ONE kernel, 16B/lane loads ----
// nontemporal loads: the 262MB fp32 W is touched exactly once; keep it out of
// L3 so Xq/Wq (74MB, re-read by gemm) stay resident.
__global__ void quant_all(const float* __restrict__ X, const float* __restrict__ W,
                          int* __restrict__ Xq, int* __restrict__ Wq,
                          float* __restrict__ accum) {
    const int NX = BT * H / 4;
    const int NW = (int)((size_t)V * H / 4);
    int i = blockIdx.x * blockDim.x + threadIdx.x;
    if (i == 0) { accum[0] = 0.f; accum[1] = 0.f; }
    if (i < NX) {
        f4v v = __builtin_nontemporal_load((const f4v*)X + i);
        int p = __builtin_amdgcn_cvt_pk_fp8_f32(v.x, v.y, 0, false);
        p     = __builtin_amdgcn_cvt_pk_fp8_f32(v.z, v.w, p, true);
        Xq[i] = p;
    } else if (i < NX + NW) {
        int j = i - NX;
        f4v v = __builtin_nontemporal_load((const f4v*)W + j);
        int p = __builtin_amdgcn_cvt_pk_fp8_f32(v.x * WSCALE, v.y * WSCALE, 0, false);
        p     = __builtin_amdgcn_cvt_pk_fp8_f32(v.z * WSCALE, v.w * WSCALE, p, true);
        Wq[j] = p;
    }
}

// ---------------- fused fp8 GEMM tile + online LSE partials ----------------
// 256x256 tile, 8 waves (2Mx4N), per-wave 128x64 output, BK=128.
// Pipeline: double-buffered 64KB K-tiles; ALL loads for tile t+1 issued
// BEFORE computing tile t (full-tile issue->use lead), ONE barrier per
// K-tile (compiler's vmcnt(0)+s_barrier). No intra-tile barriers: each wave
// reads only its own A-half / B-strip of the resident buffer.
__global__ __launch_bounds__(512, 2) void gemm_lse(
    const uint8_t* __restrict__ Xq,          // [BT,H] fp8
    const uint8_t* __restrict__ Wq,          // [V,H]  fp8 (pre-scaled x64)
    const float* __restrict__ bias,          // [V]
    const int*  __restrict__ target,         // [BT]
    float* __restrict__ part_m,              // [BT][PJ]
    float* __restrict__ part_l,              // [BT][PJ]
    float* __restrict__ tgt_logit)           // [BT]
{
    // 128KB LDS: [A0 32K][B0 32K][A1 32K][B1 32K]; epilogue aliases the
    // front 9KB for red_m/red_l/tgts after the final barrier.
    // NOTE: no pointer ARRAYS into __shared__ (hipcc lowers them as static
    // addrspacecast initializers -> compile error); compute bases from `cur`.
    __shared__ __align__(16) uint8_t smem[131072];

    const int tid  = threadIdx.x;
    const int lane = tid & 63;
    const int wave = tid >> 6;       // 0..7
    const int wm   = wave >> 2;      // 128-row half
    const int wn   = wave & 3;       // 64-col strip

    // XCD-bijective swizzle: 2000 blocks % 8 == 0, chunk of 250 per XCD.
    // Consecutive swz share the same W-tile (rb fastest) for L2 locality.
    const int bid = blockIdx.x;
    const int swz = (bid & 7) * 250 + (bid >> 3);
    const int rbk = swz & 15;        // 16 row tiles
    const int cbk = swz >> 4;        // 125 col tiles
    const int row0 = rbk * BM;
    const int col0 = cbk * BN;

    f32x4 acc[8][4];
#pragma unroll
    for (int i = 0; i < 8; i++)
#pragma unroll
        for (int j = 0; j < 4; j++) acc[i][j] = (f32x4){0.f, 0.f, 0.f, 0.f};

    // staging: lane l -> row 8g + l/8, physical chunk l%8 holds logical (l%8)^(l/8)
    const int srow   = lane >> 3;                    // 0..7
    const int schunk = ((lane & 7) ^ srow) * 16;     // pre-swizzled global byte off
    const uint8_t* Aptr = Xq + (size_t)(row0 + 32 * wave + srow) * H + schunk;
    const uint8_t* Bptr = Wq + (size_t)(col0 + 32 * wave + srow) * H + schunk;

    auto stage = [&](int buf, const uint8_t* ap_, const uint8_t* bp_) {
        uint8_t* as_ = smem + buf * 65536;
        uint8_t* bs_ = smem + buf * 65536 + 32768;
#pragma unroll
        for (int L = 0; L < 4; L++) {
            const int g = 4 * wave + L;              // rows 8g..8g+7
            async_load16(ap_ + (size_t)(8 * L) * H, as_ + g * 1024);
            async_load16(bp_ + (size_t)(8 * L) * H, bs_ + g * 1024);
        }
    };

    // prologue: tile 0 -> buf0
    stage(0, Aptr, Bptr);
    __syncthreads();                                 // vmcnt(0) drain + barrier

    const int lr  = lane & 15;
    const int g32 = lane >> 4;                       // k-group: logical chunks {2g,2g+1}

    for (int t = 0; t < H / BK; ++t) {
        const int cur = t & 1;
        if (t < H / BK - 1) {                        // issue next tile EARLY (lead)
            Aptr += BK; Bptr += BK;
            stage(cur ^ 1, Aptr, Bptr);
        }
        const uint8_t* As = smem + cur * 65536;
        const uint8_t* Bs = smem + cur * 65536 + 32768;
        union Frag { int4 q[2]; v8i v; };
        Frag bf[4];
#pragma unroll
        for (int j = 0; j < 4; j++) {
            const int r  = wn * 64 + j * 16 + lr;
            const int p0 = (2 * g32) ^ (r & 7);
            const int4* base = (const int4*)&Bs[r * BK];
            bf[j].q[0] = base[p0];
            bf[j].q[1] = base[p0 ^ 1];
        }
#pragma unroll
        for (int i = 0; i < 8; i++) {
            const int r  = wm * 128 + i * 16 + lr;
            const int p0 = (2 * g32) ^ (r & 7);
            const int4* base = (const int4*)&As[r * BK];
            Frag af;
            af.q[0] = base[p0];
            af.q[1] = base[p0 ^ 1];
            __builtin_amdgcn_s_setprio(1);
#pragma unroll
            for (int j = 0; j < 4; j++)
                acc[i][j] = __builtin_amdgcn_mfma_scale_f32_16x16x128_f8f6f4(
                    af.v, bf[j].v, acc[i][j],
                    0 /*A=e4m3*/, 0 /*B=e4m3*/,
                    0, 0x7f7f7f7f, 0, 0x7f7f7f7f);   // all scales = 2^0
            __builtin_amdgcn_s_setprio(0);
        }
        __syncthreads();   // one barrier/tile: drains t+1 loads (issued a full
                           // tile ago) + frees buf[cur] for overwrite
    }

    // ---- epilogue: unscale, bias, target grab, max-first reduce, ONE exp pass
    float* red_m = (float*)smem;                 // [4][256]
    float* red_l = (float*)(smem + 4096);        // [4][256]
    int*   tgts  = (int*)(smem + 8192);          // [256]

    if (tid < 256) tgts[tid] = target[row0 + tid];
    __syncthreads();

    const int quad = lane >> 4;
    float bj[4];
#pragma unroll
    for (int j = 0; j < 4; j++) bj[j] = bias[col0 + wn * 64 + j * 16 + lr];

#pragma unroll
    for (int i = 0; i < 8; i++) {
#pragma unroll
        for (int r = 0; r < 4; r++) {
            const int rit = wm * 128 + i * 16 + quad * 4 + r;  // C/D: row=quad*4+reg
            float v[4];
#pragma unroll
            for (int j = 0; j < 4; j++) v[j] = acc[i][j][r] * INV_WSCALE + bj[j];
            const int tg = tgts[rit];
#pragma unroll
            for (int j = 0; j < 4; j++)
                if (col0 + wn * 64 + j * 16 + lr == tg)
                    tgt_logit[row0 + rit] = v[j];  // exactly one writer globally
            float mx = fmaxf(fmaxf(v[0], v[1]), fmaxf(v[2], v[3]));
#pragma unroll
            for (int d = 1; d < 16; d <<= 1) mx = fmaxf(mx, __shfl_xor(mx, d));
            float se = __expf(v[0] - mx) + __expf(v[1] - mx) +
                       __expf(v[2] - mx) + __expf(v[3] - mx);
#pragma unroll
            for (int d = 1; d < 16; d <<= 1) se += __shfl_xor(se, d);
            if (lr == 0) { red_m[wn * 256 + rit] = mx; red_l[wn * 256 + rit] = se; }
        }
    }
    __syncthreads();
    if (tid < 256) {
        float M = red_m[tid];
        float m1 = red_m[256 + tid], m2 = red_m[512 + tid], m3 = red_m[768 + tid];
        M = fmaxf(fmaxf(M, m1), fmaxf(m2, m3));
        float L = red_l[tid]       * __expf(red_m[tid]       - M)
                + red_l[256 + tid] * __expf(m1 - M)
                + red_l[512 + tid] * __expf(m2 - M)
                + red_l[768 + tid] * __expf(m3 - M);
        part_m[(size_t)(row0 + tid) * PJ + cbk] = M;
        part_l[(size_t)(row0 + tid) * PJ + cbk] = L;
    }
}

// ------- merge partials: one WAVE per token, lane-parallel over V-tiles -----
__global__ void finalize(const float* __restrict__ part_m,
                         const float* __restrict__ part_l,
                         const float* __restrict__ tgt_logit,
                         const int*  __restrict__ target,
                         float* __restrict__ accum)  // accum[0]=sum, accum[1]=count
{
    const int wave = threadIdx.x >> 6, lane = threadIdx.x & 63;
    const int t = blockIdx.x * 4 + wave;             // grid = BT/4
    float m[2], l[2];
#pragma unroll
    for (int c = 0; c < 2; c++) {
        const int j = c * 64 + lane;
        const bool ok = j < NVT;
        m[c] = ok ? part_m[(size_t)t * PJ + j] : -1e30f;
        l[c] = ok ? part_l[(size_t)t * PJ + j] : 0.f;
    }
    float M = fmaxf(m[0], m[1]);
#pragma unroll
    for (int d = 1; d < 64; d <<= 1) M = fmaxf(M, __shfl_xor(M, d));
    float S = l[0] * __expf(m[0] - M) + l[1] * __expf(m[1] - M);
#pragma unroll
    for (int d = 1; d < 64; d <<= 1) S += __shfl_xor(S, d);

    __shared__ float sm[4], sc[4];
    if (lane == 0) {
        const int tg = target[t];
        float loss = 0.f, cnt = 0.f;
        if (tg != -100) {
            loss = (M + __logf(S)) - tgt_logit[t];
            cnt  = 1.f;
        }
        sm[wave] = loss; sc[wave] = cnt;
    }
    __syncthreads();
    if (threadIdx.x == 0) {
        float Ls = sm[0] + sm[1] + sm[2] + sm[3];
        float Cs = sc[0] + sc[1] + sc[2] + sc[3];
        atomicAdd(&accum[0], Ls);
        atomicAdd(&accum[1], Cs);
    }
}

__global__ void final_div(const float* __restrict__ accum, float* __restrict__ out) {
    out[0] = accum[0] / fmaxf(accum[1], 1.f);
}

extern "C" void kernel_launch(void* const* d_in, const int* in_sizes, int n_in,
                              void* d_out, int out_size, void* d_ws, size_t ws_size,
                              hipStream_t stream) {
    const float* x      = (const float*)d_in[0];
    const int*   target = (const int*)d_in[1];
    const float* w      = (const float*)d_in[2];
    const float* bias   = (const float*)d_in[3];

    char* ws = (char*)d_ws;
    size_t off = 0;
    auto alloc = [&](size_t bytes) {
        void* p = ws + off;
        off += (bytes + 255) & ~(size_t)255;
        return p;
    };
    uint8_t* Xq   = (uint8_t*)alloc((size_t)BT * H);
    uint8_t* Wq   = (uint8_t*)alloc((size_t)V * H);
    float* part_m = (float*)alloc((size_t)BT * PJ * 4);
    float* part_l = (float*)alloc((size_t)BT * PJ * 4);
    float* tgtl   = (float*)alloc((size_t)BT * 4);
    float* accum  = (float*)alloc(256);

    const int nq = BT * H / 4 + (int)((size_t)V * H / 4);
    quant_all<<<(nq + 255) / 256, 256, 0, stream>>>(
        x, w, (int*)Xq, (int*)Wq, accum);

    gemm_lse<<<NRT * NVT, 512, 0, stream>>>(Xq, Wq, bias, target, part_m, part_l, tgtl);

    finalize<<<BT / 4, 256, 0, stream>>>(part_m, part_l, tgtl, target, accum);

    final_div<<<1, 1, 0, stream>>>(accum, (float*)d_out);
}

// Round 4
// 735.736 us; speedup vs baseline: 1.0048x; 1.0048x over previous
//
#include <hip/hip_runtime.h>
#include <cstdint>

#define BT 4096
#define H  2048
#define V  32000
#define BM 256
#define BN 256
#define BK 128          // fp8 bytes == elements per K-tile
#define NRT (BT/BM)     // 16
#define NVT (V/BN)      // 125
#define PJ  128         // padded partials row stride (floats)
#define WSCALE 64.0f
#define INV_WSCALE 0.015625f

typedef int   v8i   __attribute__((ext_vector_type(8)));
typedef float f32x4 __attribute__((ext_vector_type(4)));
typedef float f4v   __attribute__((ext_vector_type(4)));

__device__ __forceinline__ void async_load16(const void* g, void* l) {
    __builtin_amdgcn_global_load_lds(
        (__attribute__((address_space(1))) uint32_t*)(void*)g,
        (__attribute__((address_space(3))) uint32_t*)l, 16, 0, 0);
}

// ------- quantize X and W fp32 -> fp8 e4m3 in ONE kernel, 16B/lane loads ----
__global__ void quant_all(const float* __restrict__ X, const float* __restrict__ W,
                          int* __restrict__ Xq, int* __restrict__ Wq,
                          float* __restrict__ accum) {
    const int NX = BT * H / 4;
    const int NW = (int)((size_t)V * H / 4);
    int i = blockIdx.x * blockDim.x + threadIdx.x;
    if (i == 0) { accum[0] = 0.f; accum[1] = 0.f; }
    if (i < NX) {
        f4v v = __builtin_nontemporal_load((const f4v*)X + i);
        int p = __builtin_amdgcn_cvt_pk_fp8_f32(v.x, v.y, 0, false);
        p     = __builtin_amdgcn_cvt_pk_fp8_f32(v.z, v.w, p, true);
        Xq[i] = p;
    } else if (i < NX + NW) {
        int j = i - NX;
        f4v v = __builtin_nontemporal_load((const f4v*)W + j);
        int p = __builtin_amdgcn_cvt_pk_fp8_f32(v.x * WSCALE, v.y * WSCALE, 0, false);
        p     = __builtin_amdgcn_cvt_pk_fp8_f32(v.z * WSCALE, v.w * WSCALE, p, true);
        Wq[j] = p;
    }
}

// ---------------- fused fp8 GEMM tile + online LSE partials ----------------
// 256x256 tile, 8 waves (2Mx4N), per-wave 128x64 output, BK=128.
// Schedule fix vs Round 1 (which stalled: read->use dependency on every
// A-frag, no cover at 1 block/CU): B-frags register-resident per tile;
// A-frag PAIRS streamed with one-pair lookahead so each ds_read has an
// 8-MFMA shadow. Register budget: 128 acc (AGPR) + 32 bf + 2x16 af pairs
// + misc ~= 125 VGPR -> fits 2 waves/SIMD without spill.
__global__ __launch_bounds__(512, 2) void gemm_lse(
    const uint8_t* __restrict__ Xq,          // [BT,H] fp8
    const uint8_t* __restrict__ Wq,          // [V,H]  fp8 (pre-scaled x64)
    const float* __restrict__ bias,          // [V]
    const int*  __restrict__ target,         // [BT]
    float* __restrict__ part_m,              // [BT][PJ]
    float* __restrict__ part_l,              // [BT][PJ]
    float* __restrict__ tgt_logit)           // [BT]
{
    // 128KB LDS: [A0 32K][B0 32K][A1 32K][B1 32K]; epilogue aliases front 9KB.
    __shared__ __align__(16) uint8_t smem[131072];

    const int tid  = threadIdx.x;
    const int lane = tid & 63;
    const int wave = tid >> 6;       // 0..7
    const int wm   = wave >> 2;      // 128-row half
    const int wn   = wave & 3;       // 64-col strip

    // XCD-bijective swizzle: 2000 blocks % 8 == 0, chunk of 250 per XCD.
    const int bid = blockIdx.x;
    const int swz = (bid & 7) * 250 + (bid >> 3);
    const int rbk = swz & 15;        // 16 row tiles
    const int cbk = swz >> 4;        // 125 col tiles
    const int row0 = rbk * BM;
    const int col0 = cbk * BN;

    f32x4 acc[8][4];
#pragma unroll
    for (int i = 0; i < 8; i++)
#pragma unroll
        for (int j = 0; j < 4; j++) acc[i][j] = (f32x4){0.f, 0.f, 0.f, 0.f};

    // staging: lane l -> row 8g + l/8, physical chunk l%8 holds logical (l%8)^(l/8)
    const int srow   = lane >> 3;                    // 0..7
    const int schunk = ((lane & 7) ^ srow) * 16;     // pre-swizzled global byte off
    const uint8_t* Aptr = Xq + (size_t)(row0 + 32 * wave + srow) * H + schunk;
    const uint8_t* Bptr = Wq + (size_t)(col0 + 32 * wave + srow) * H + schunk;

    auto stage = [&](int buf, const uint8_t* ap_, const uint8_t* bp_) {
        uint8_t* as_ = smem + buf * 65536;
        uint8_t* bs_ = smem + buf * 65536 + 32768;
#pragma unroll
        for (int L = 0; L < 4; L++) {
            const int g = 4 * wave + L;              // rows 8g..8g+7
            async_load16(ap_ + (size_t)(8 * L) * H, as_ + g * 1024);
            async_load16(bp_ + (size_t)(8 * L) * H, bs_ + g * 1024);
        }
    };

    // prologue: tile 0 -> buf0
    stage(0, Aptr, Bptr);
    __syncthreads();                                 // vmcnt(0) drain + barrier

    const int lr  = lane & 15;
    const int g32 = lane >> 4;                       // k-group: logical chunks {2g,2g+1}

    union Frag { int4 q[2]; v8i v; };

    for (int t = 0; t < H / BK; ++t) {
        const int cur = t & 1;
        if (t < H / BK - 1) {                        // issue next tile EARLY (max lead)
            Aptr += BK; Bptr += BK;
            stage(cur ^ 1, Aptr, Bptr);
        }
        const uint8_t* As = smem + cur * 65536;
        const uint8_t* Bs = smem + cur * 65536 + 32768;

        auto lda = [&](int i, Frag& f) {
            const int r  = wm * 128 + i * 16 + lr;
            const int p0 = (2 * g32) ^ (r & 7);
            const int4* base = (const int4*)&As[r * BK];
            f.q[0] = base[p0];
            f.q[1] = base[p0 ^ 1];
        };

        // B-frags: register-resident for the whole tile (8 ds_read_b128)
        Frag bf[4];
#pragma unroll
        for (int j = 0; j < 4; j++) {
            const int r  = wn * 64 + j * 16 + lr;
            const int p0 = (2 * g32) ^ (r & 7);
            const int4* base = (const int4*)&Bs[r * BK];
            bf[j].q[0] = base[p0];
            bf[j].q[1] = base[p0 ^ 1];
        }

        // A-pairs streamed with one-pair lookahead (static after unroll)
        Frag a0, a1, n0, n1;
        lda(0, a0);
        lda(1, a1);
#pragma unroll
        for (int q = 0; q < 4; q++) {
            if (q < 3) {                             // issue next pair BEFORE MFMAs
                lda(2 * q + 2, n0);
                lda(2 * q + 3, n1);
            }
            __builtin_amdgcn_s_setprio(1);
#pragma unroll
            for (int j = 0; j < 4; j++)
                acc[2 * q][j] = __builtin_amdgcn_mfma_scale_f32_16x16x128_f8f6f4(
                    a0.v, bf[j].v, acc[2 * q][j],
                    0, 0, 0, 0x7f7f7f7f, 0, 0x7f7f7f7f);
#pragma unroll
            for (int j = 0; j < 4; j++)
                acc[2 * q + 1][j] = __builtin_amdgcn_mfma_scale_f32_16x16x128_f8f6f4(
                    a1.v, bf[j].v, acc[2 * q + 1][j],
                    0, 0, 0, 0x7f7f7f7f, 0, 0x7f7f7f7f);
            __builtin_amdgcn_s_setprio(0);
            a0 = n0;
            a1 = n1;
        }
        __syncthreads();   // one barrier/tile: drains t+1 loads (issued a full
                           // tile of MFMA ago) + frees buf[cur]
    }

    // ---- epilogue: unscale, bias, target grab, max-first reduce, ONE exp pass
    float* red_m = (float*)smem;                 // [4][256]
    float* red_l = (float*)(smem + 4096);        // [4][256]
    int*   tgts  = (int*)(smem + 8192);          // [256]

    if (tid < 256) tgts[tid] = target[row0 + tid];
    __syncthreads();

    const int quad = lane >> 4;
    float bj[4];
#pragma unroll
    for (int j = 0; j < 4; j++) bj[j] = bias[col0 + wn * 64 + j * 16 + lr];

#pragma unroll
    for (int i = 0; i < 8; i++) {
#pragma unroll
        for (int r = 0; r < 4; r++) {
            const int rit = wm * 128 + i * 16 + quad * 4 + r;  // C/D: row=quad*4+reg
            float v[4];
#pragma unroll
            for (int j = 0; j < 4; j++) v[j] = acc[i][j][r] * INV_WSCALE + bj[j];
            const int tg = tgts[rit];
#pragma unroll
            for (int j = 0; j < 4; j++)
                if (col0 + wn * 64 + j * 16 + lr == tg)
                    tgt_logit[row0 + rit] = v[j];  // exactly one writer globally
            float mx = fmaxf(fmaxf(v[0], v[1]), fmaxf(v[2], v[3]));
#pragma unroll
            for (int d = 1; d < 16; d <<= 1) mx = fmaxf(mx, __shfl_xor(mx, d));
            float se = __expf(v[0] - mx) + __expf(v[1] - mx) +
                       __expf(v[2] - mx) + __expf(v[3] - mx);
#pragma unroll
            for (int d = 1; d < 16; d <<= 1) se += __shfl_xor(se, d);
            if (lr == 0) { red_m[wn * 256 + rit] = mx; red_l[wn * 256 + rit] = se; }
        }
    }
    __syncthreads();
    if (tid < 256) {
        float M = red_m[tid];
        float m1 = red_m[256 + tid], m2 = red_m[512 + tid], m3 = red_m[768 + tid];
        M = fmaxf(fmaxf(M, m1), fmaxf(m2, m3));
        float L = red_l[tid]       * __expf(red_m[tid]       - M)
                + red_l[256 + tid] * __expf(m1 - M)
                + red_l[512 + tid] * __expf(m2 - M)
                + red_l[768 + tid] * __expf(m3 - M);
        part_m[(size_t)(row0 + tid) * PJ + cbk] = M;
        part_l[(size_t)(row0 + tid) * PJ + cbk] = L;
    }
}

// ------- merge partials: one WAVE per token, lane-parallel over V-tiles -----
__global__ void finalize(const float* __restrict__ part_m,
                         const float* __restrict__ part_l,
                         const float* __restrict__ tgt_logit,
                         const int*  __restrict__ target,
                         float* __restrict__ accum)  // accum[0]=sum, accum[1]=count
{
    const int wave = threadIdx.x >> 6, lane = threadIdx.x & 63;
    const int t = blockIdx.x * 4 + wave;             // grid = BT/4
    float m[2], l[2];
#pragma unroll
    for (int c = 0; c < 2; c++) {
        const int j = c * 64 + lane;
        const bool ok = j < NVT;
        m[c] = ok ? part_m[(size_t)t * PJ + j] : -1e30f;
        l[c] = ok ? part_l[(size_t)t * PJ + j] : 0.f;
    }
    float M = fmaxf(m[0], m[1]);
#pragma unroll
    for (int d = 1; d < 64; d <<= 1) M = fmaxf(M, __shfl_xor(M, d));
    float S = l[0] * __expf(m[0] - M) + l[1] * __expf(m[1] - M);
#pragma unroll
    for (int d = 1; d < 64; d <<= 1) S += __shfl_xor(S, d);

    __shared__ float sm[4], sc[4];
    if (lane == 0) {
        const int tg = target[t];
        float loss = 0.f, cnt = 0.f;
        if (tg != -100) {
            loss = (M + __logf(S)) - tgt_logit[t];
            cnt  = 1.f;
        }
        sm[wave] = loss; sc[wave] = cnt;
    }
    __syncthreads();
    if (threadIdx.x == 0) {
        float Ls = sm[0] + sm[1] + sm[2] + sm[3];
        float Cs = sc[0] + sc[1] + sc[2] + sc[3];
        atomicAdd(&accum[0], Ls);
        atomicAdd(&accum[1], Cs);
    }
}

__global__ void final_div(const float* __restrict__ accum, float* __restrict__ out) {
    out[0] = accum[0] / fmaxf(accum[1], 1.f);
}

extern "C" void kernel_launch(void* const* d_in, const int* in_sizes, int n_in,
                              void* d_out, int out_size, void* d_ws, size_t ws_size,
                              hipStream_t stream) {
    const float* x      = (const float*)d_in[0];
    const int*   target = (const int*)d_in[1];
    const float* w      = (const float*)d_in[2];
    const float* bias   = (const float*)d_in[3];

    char* ws = (char*)d_ws;
    size_t off = 0;
    auto alloc = [&](size_t bytes) {
        void* p = ws + off;
        off += (bytes + 255) & ~(size_t)255;
        return p;
    };
    uint8_t* Xq   = (uint8_t*)alloc((size_t)BT * H);
    uint8_t* Wq   = (uint8_t*)alloc((size_t)V * H);
    float* part_m = (float*)alloc((size_t)BT * PJ * 4);
    float* part_l = (float*)alloc((size_t)BT * PJ * 4);
    float* tgtl   = (float*)alloc((size_t)BT * 4);
    float* accum  = (float*)alloc(256);

    const int nq = BT * H / 4 + (int)((size_t)V * H / 4);
    quant_all<<<(nq + 255) / 256, 256, 0, stream>>>(
        x, w, (int*)Xq, (int*)Wq, accum);

    gemm_lse<<<NRT * NVT, 512, 0, stream>>>(Xq, Wq, bias, target, part_m, part_l, tgtl);

    finalize<<<BT / 4, 256, 0, stream>>>(part_m, part_l, tgtl, target, accum);

    final_div<<<1, 1, 0, stream>>>(accum, (float*)d_out);
}

// Round 6
// 733.778 us; speedup vs baseline: 1.0075x; 1.0027x over previous
//
#include <hip/hip_runtime.h>
#include <cstdint>

#define BT 4096
#define H  2048
#define V  32000
#define BM 256
#define BN 256
#define BK 128          // fp8 bytes == elements per K-tile
#define NT (H/BK)       // 16 K-tiles
#define NRT (BT/BM)     // 16
#define NVT (V/BN)      // 125
#define PJ  128         // padded partials row stride (floats)
#define WSCALE 64.0f
#define INV_WSCALE 0.015625f

typedef int   v8i   __attribute__((ext_vector_type(8)));
typedef float f32x4 __attribute__((ext_vector_type(4)));
typedef float f4v   __attribute__((ext_vector_type(4)));

__device__ __forceinline__ void async_load16(const void* g, void* l) {
    __builtin_amdgcn_global_load_lds(
        (__attribute__((address_space(1))) uint32_t*)(void*)g,
        (__attribute__((address_space(3))) uint32_t*)l, 16, 0, 0);
}

// ------- quantize X and W fp32 -> fp8 e4m3 in ONE kernel, 16B/lane loads ----
__global__ void quant_all(const float* __restrict__ X, const float* __restrict__ W,
                          int* __restrict__ Xq, int* __restrict__ Wq,
                          float* __restrict__ accum) {
    const int NX = BT * H / 4;
    const int NW = (int)((size_t)V * H / 4);
    int i = blockIdx.x * blockDim.x + threadIdx.x;
    if (i == 0) { accum[0] = 0.f; accum[1] = 0.f; }
    if (i < NX) {
        f4v v = __builtin_nontemporal_load((const f4v*)X + i);
        int p = __builtin_amdgcn_cvt_pk_fp8_f32(v.x, v.y, 0, false);
        p     = __builtin_amdgcn_cvt_pk_fp8_f32(v.z, v.w, p, true);
        Xq[i] = p;
    } else if (i < NX + NW) {
        int j = i - NX;
        f4v v = __builtin_nontemporal_load((const f4v*)W + j);
        int p = __builtin_amdgcn_cvt_pk_fp8_f32(v.x * WSCALE, v.y * WSCALE, 0, false);
        p     = __builtin_amdgcn_cvt_pk_fp8_f32(v.z * WSCALE, v.w * WSCALE, p, true);
        Wq[j] = p;
    }
}

// ---------------- fused fp8 GEMM tile + online LSE partials ----------------
// 256x256 tile, 8 waves (2Mx4N), per-wave 128x64 output, BK=128.
// m201 phase template ported: 4 phases per K-tile, each
//   { ds_read subtile (+4 gloads in ph0/ph1) -> s_barrier -> lgkmcnt(0)
//     -> sched_barrier(0) -> setprio(1) 8 MFMA setprio(0) -> s_barrier }
// Tile boundary: vmcnt(0) (loads issued >=2 phases earlier) + barrier.
// Raw s_barrier (NOT __syncthreads: that drains vmcnt to 0 with zero shadow).
__global__ __launch_bounds__(512, 2) void gemm_lse(
    const uint8_t* __restrict__ Xq,          // [BT,H] fp8
    const uint8_t* __restrict__ Wq,          // [V,H]  fp8 (pre-scaled x64)
    const float* __restrict__ bias,          // [V]
    const int*  __restrict__ target,         // [BT]
    float* __restrict__ part_m,              // [BT][PJ]
    float* __restrict__ part_l,              // [BT][PJ]
    float* __restrict__ tgt_logit)           // [BT]
{
    // 128KB LDS: [A0 32K][B0 32K][A1 32K][B1 32K]; epilogue aliases front 9KB.
    __shared__ __align__(16) uint8_t smem[131072];

    const int tid  = threadIdx.x;
    const int lane = tid & 63;
    const int wave = tid >> 6;       // 0..7
    const int wm   = wave >> 2;      // 128-row half
    const int wn   = wave & 3;       // 64-col strip

    // XCD-bijective swizzle: 2000 blocks % 8 == 0, chunk of 250 per XCD.
    const int bid = blockIdx.x;
    const int swz = (bid & 7) * 250 + (bid >> 3);
    const int rbk = swz & 15;        // 16 row tiles
    const int cbk = swz >> 4;        // 125 col tiles
    const int row0 = rbk * BM;
    const int col0 = cbk * BN;

    f32x4 acc[8][4];
#pragma unroll
    for (int i = 0; i < 8; i++)
#pragma unroll
        for (int j = 0; j < 4; j++) acc[i][j] = (f32x4){0.f, 0.f, 0.f, 0.f};

    // staging: lane l -> row 8g + l/8, physical chunk l%8 holds logical (l%8)^(l/8)
    const int srow   = lane >> 3;                    // 0..7
    const int schunk = ((lane & 7) ^ srow) * 16;     // pre-swizzled global byte off
    // Aptr/Bptr always point at the NEXT tile to stage.
    const uint8_t* Aptr = Xq + (size_t)(row0 + 32 * wave + srow) * H + schunk;
    const uint8_t* Bptr = Wq + (size_t)(col0 + 32 * wave + srow) * H + schunk;

    auto stageA = [&](int buf) {
        uint8_t* as_ = smem + buf * 65536;
#pragma unroll
        for (int L = 0; L < 4; L++)
            async_load16(Aptr + (size_t)(8 * L) * H, as_ + (4 * wave + L) * 1024);
    };
    auto stageB = [&](int buf) {
        uint8_t* bs_ = smem + buf * 65536 + 32768;
#pragma unroll
        for (int L = 0; L < 4; L++)
            async_load16(Bptr + (size_t)(8 * L) * H, bs_ + (4 * wave + L) * 1024);
    };

    // prologue: tile 0 -> buf0 (full drain: nothing to overlap yet)
    stageA(0); stageB(0);
    Aptr += BK; Bptr += BK;
    asm volatile("s_waitcnt vmcnt(0)" ::: "memory");
    __builtin_amdgcn_s_barrier();

    const int lr  = lane & 15;
    const int g32 = lane >> 4;       // k-group: logical chunks {2g,2g+1}

    union Frag { int4 q[2]; v8i v; };

    for (int t = 0; t < NT; ++t) {
        const int cur = t & 1;
        const bool pf = (t < NT - 1);
        const uint8_t* As = smem + cur * 65536;
        const uint8_t* Bs = smem + cur * 65536 + 32768;

        auto lda = [&](int i, Frag& f) {
            const int r  = wm * 128 + i * 16 + lr;
            const int p0 = (2 * g32) ^ (r & 7);
            const int4* base = (const int4*)&As[r * BK];
            f.q[0] = base[p0];
            f.q[1] = base[p0 ^ 1];
        };

        Frag bf[4];                                  // live across all 4 phases
#pragma unroll
        for (int p = 0; p < 4; ++p) {
            // ---- phase p reads ----
            Frag a0, a1;
            lda(2 * p,     a0);
            lda(2 * p + 1, a1);
            if (p == 0) {
#pragma unroll
                for (int j = 0; j < 4; j++) {
                    const int r  = wn * 64 + j * 16 + lr;
                    const int p0 = (2 * g32) ^ (r & 7);
                    const int4* base = (const int4*)&Bs[r * BK];
                    bf[j].q[0] = base[p0];
                    bf[j].q[1] = base[p0 ^ 1];
                }
                if (pf) stageA(cur ^ 1);             // 4 gloads, ~4 phases of shadow
                asm volatile("s_waitcnt lgkmcnt(8)" ::: "memory");  // 12 reads in flight
            }
            if (p == 1 && pf) stageB(cur ^ 1);       // 4 gloads, ~3 phases of shadow
            __builtin_amdgcn_s_barrier();
            asm volatile("s_waitcnt lgkmcnt(0)" ::: "memory");
            __builtin_amdgcn_sched_barrier(0);       // rule #18: pin MFMA below wait
            __builtin_amdgcn_s_setprio(1);
#pragma unroll
            for (int j = 0; j < 4; j++)
                acc[2 * p][j] = __builtin_amdgcn_mfma_scale_f32_16x16x128_f8f6f4(
                    a0.v, bf[j].v, acc[2 * p][j],
                    0, 0, 0, 0x7f7f7f7f, 0, 0x7f7f7f7f);
#pragma unroll
            for (int j = 0; j < 4; j++)
                acc[2 * p + 1][j] = __builtin_amdgcn_mfma_scale_f32_16x16x128_f8f6f4(
                    a1.v, bf[j].v, acc[2 * p + 1][j],
                    0, 0, 0, 0x7f7f7f7f, 0, 0x7f7f7f7f);
            __builtin_amdgcn_s_setprio(0);
            if (p < 3) __builtin_amdgcn_s_barrier();
        }
        // tile boundary: drain this wave's 8 prefetch loads (issued phases 0-1,
        // >=2 MFMA phases ago), then barrier so all waves' stages are visible.
        if (pf) {
            Aptr += BK; Bptr += BK;
            asm volatile("s_waitcnt vmcnt(0)" ::: "memory");
        }
        __builtin_amdgcn_s_barrier();
    }

    // ---- epilogue: unscale, bias, target grab, max-first reduce, ONE exp pass
    float* red_m = (float*)smem;                 // [4][256]
    float* red_l = (float*)(smem + 4096);        // [4][256]
    int*   tgts  = (int*)(smem + 8192);          // [256]

    if (tid < 256) tgts[tid] = target[row0 + tid];
    __syncthreads();

    const int quad = lane >> 4;
    float bj[4];
#pragma unroll
    for (int j = 0; j < 4; j++) bj[j] = bias[col0 + wn * 64 + j * 16 + lr];

#pragma unroll
    for (int i = 0; i < 8; i++) {
#pragma unroll
        for (int r = 0; r < 4; r++) {
            const int rit = wm * 128 + i * 16 + quad * 4 + r;  // C/D: row=quad*4+reg
            float v[4];
#pragma unroll
            for (int j = 0; j < 4; j++) v[j] = acc[i][j][r] * INV_WSCALE + bj[j];
            const int tg = tgts[rit];
#pragma unroll
            for (int j = 0; j < 4; j++)
                if (col0 + wn * 64 + j * 16 + lr == tg)
                    tgt_logit[row0 + rit] = v[j];  // exactly one writer globally
            float mx = fmaxf(fmaxf(v[0], v[1]), fmaxf(v[2], v[3]));
#pragma unroll
            for (int d = 1; d < 16; d <<= 1) mx = fmaxf(mx, __shfl_xor(mx, d));
            float se = __expf(v[0] - mx) + __expf(v[1] - mx) +
                       __expf(v[2] - mx) + __expf(v[3] - mx);
#pragma unroll
            for (int d = 1; d < 16; d <<= 1) se += __shfl_xor(se, d);
            if (lr == 0) { red_m[wn * 256 + rit] = mx; red_l[wn * 256 + rit] = se; }
        }
    }
    __syncthreads();
    if (tid < 256) {
        float M = red_m[tid];
        float m1 = red_m[256 + tid], m2 = red_m[512 + tid], m3 = red_m[768 + tid];
        M = fmaxf(fmaxf(M, m1), fmaxf(m2, m3));
        float L = red_l[tid]       * __expf(red_m[tid]       - M)
                + red_l[256 + tid] * __expf(m1 - M)
                + red_l[512 + tid] * __expf(m2 - M)
                + red_l[768 + tid] * __expf(m3 - M);
        part_m[(size_t)(row0 + tid) * PJ + cbk] = M;
        part_l[(size_t)(row0 + tid) * PJ + cbk] = L;
    }
}

// ------- merge partials: one WAVE per token, lane-parallel over V-tiles -----
__global__ void finalize(const float* __restrict__ part_m,
                         const float* __restrict__ part_l,
                         const float* __restrict__ tgt_logit,
                         const int*  __restrict__ target,
                         float* __restrict__ accum)  // accum[0]=sum, accum[1]=count
{
    const int wave = threadIdx.x >> 6, lane = threadIdx.x & 63;
    const int t = blockIdx.x * 4 + wave;             // grid = BT/4
    float m[2], l[2];
#pragma unroll
    for (int c = 0; c < 2; c++) {
        const int j = c * 64 + lane;
        const bool ok = j < NVT;
        m[c] = ok ? part_m[(size_t)t * PJ + j] : -1e30f;
        l[c] = ok ? part_l[(size_t)t * PJ + j] : 0.f;
    }
    float M = fmaxf(m[0], m[1]);
#pragma unroll
    for (int d = 1; d < 64; d <<= 1) M = fmaxf(M, __shfl_xor(M, d));
    float S = l[0] * __expf(m[0] - M) + l[1] * __expf(m[1] - M);
#pragma unroll
    for (int d = 1; d < 64; d <<= 1) S += __shfl_xor(S, d);

    __shared__ float sm[4], sc[4];
    if (lane == 0) {
        const int tg = target[t];
        float loss = 0.f, cnt = 0.f;
        if (tg != -100) {
            loss = (M + __logf(S)) - tgt_logit[t];
            cnt  = 1.f;
        }
        sm[wave] = loss; sc[wave] = cnt;
    }
    __syncthreads();
    if (threadIdx.x == 0) {
        float Ls = sm[0] + sm[1] + sm[2] + sm[3];
        float Cs = sc[0] + sc[1] + sc[2] + sc[3];
        atomicAdd(&accum[0], Ls);
        atomicAdd(&accum[1], Cs);
    }
}

__global__ void final_div(const float* __restrict__ accum, float* __restrict__ out) {
    out[0] = accum[0] / fmaxf(accum[1], 1.f);
}

extern "C" void kernel_launch(void* const* d_in, const int* in_sizes, int n_in,
                              void* d_out, int out_size, void* d_ws, size_t ws_size,
                              hipStream_t stream) {
    const float* x      = (const float*)d_in[0];
    const int*   target = (const int*)d_in[1];
    const float* w      = (const float*)d_in[2];
    const float* bias   = (const float*)d_in[3];

    char* ws = (char*)d_ws;
    size_t off = 0;
    auto alloc = [&](size_t bytes) {
        void* p = ws + off;
        off += (bytes + 255) & ~(size_t)255;
        return p;
    };
    uint8_t* Xq   = (uint8_t*)alloc((size_t)BT * H);
    uint8_t* Wq   = (uint8_t*)alloc((size_t)V * H);
    float* part_m = (float*)alloc((size_t)BT * PJ * 4);
    float* part_l = (float*)alloc((size_t)BT * PJ * 4);
    float* tgtl   = (float*)alloc((size_t)BT * 4);
    float* accum  = (float*)alloc(256);

    const int nq = BT * H / 4 + (int)((size_t)V * H / 4);
    quant_all<<<(nq + 255) / 256, 256, 0, stream>>>(
        x, w, (int*)Xq, (int*)Wq, accum);

    gemm_lse<<<NRT * NVT, 512, 0, stream>>>(Xq, Wq, bias, target, part_m, part_l, tgtl);

    finalize<<<BT / 4, 256, 0, stream>>>(part_m, part_l, tgtl, target, accum);

    final_div<<<1, 1, 0, stream>>>(accum, (float*)d_out);
}